// Round 19
// baseline (56.723 us; speedup 1.0000x reference)
//
#include <hip/hip_runtime.h>

#define B_      64
#define L_      8192
#define NB_     20
#define K_      769
#define NST3    25          // folded K-steps of 32 taps
#define NSTP3   28          // packed steps in gbuf (zeros beyond 25)
#define TB      512         // t-tile per block (8 waves x 64 t, 4 x 16-t subtiles/wave)
#define CPF     1432        // copy stride (halves): byte 2864 mod 128 = 48
#define NWF     1392        // staged halves per copy, both directions
#define XB      (8 * CPF)   // bwd region offset (halves)
#define LDS_H   (16 * CPF)  // 22912 halves = 45824 B -> 2 blocks/CU
#define CREF    2112        // bwd staging: xr[j] = xp[P0 + CREF - j]
#define PADLEN  2307        // min(3K, L-1)
#define OFFSET  1539        // PADLEN - (K-1)

typedef _Float16 half8  __attribute__((ext_vector_type(8)));
typedef float    f32x4  __attribute__((ext_vector_type(4)));

#define MFMA16(a, b, c) __builtin_amdgcn_mfma_f32_16x16x32_f16((a), (b), (c), 0, 0, 0)

// ---------------------------------------------------------------------------
// Kernel 1 (merged combine+pack): one block per fragment-band o (0..31).
// Computes folded autocorrelation g'[m] (m <= 768, scaled x1024, center /2)
// in LDS, then packs this band's mfma_16x16x32 A-fragment elements directly.
// Bands >= NB_ write zeros. Replaces bp_combine + bp_pack + gpart roundtrip.
// ---------------------------------------------------------------------------
__global__ __launch_bounds__(256) void bp_filter(
    const float* __restrict__ kern, _Float16* __restrict__ gbuf)
{
    __shared__ __align__(16) float ks[K_];
    __shared__ __align__(16) float gm[772];
    const int o   = blockIdx.x;             // 0..31
    const int tid = threadIdx.x;

    if (o < NB_)
        for (int i = tid; i < K_; i += 256) ks[i] = kern[o * K_ + i];
    __syncthreads();

    for (int m = tid; m <= 768; m += 256) {
        float acc = 0.f;
        if (o < NB_) {
            for (int j = 0; j <= m; ++j)
                acc = fmaf(ks[K_ - 1 - j], ks[m - j], acc);
            acc *= (m == 768 ? 512.0f : 1024.0f);
        }
        gm[m] = acc;
    }
    __syncthreads();

    const int tau = o >> 4;
    const int l15 = o & 15;
    for (int it = tid; it < NSTP3 * 4; it += 256) {
        const int S  = it >> 2;
        const int g4 = it & 3;
        half8 f;
        #pragma unroll
        for (int e = 0; e < 8; ++e) {
            const int tap = 32 * S + 8 * g4 + e;
            f[e] = (_Float16)((tap <= 768) ? gm[tap] : 0.f);
        }
        *((half8*)gbuf + ((2 * S + tau) * 64 + g4 * 16 + l15)) = f;
    }
}

// ---------------------------------------------------------------------------
// Kernel 2 (folded, 16x16x32, r16 structure, TB=512/8-wave): fwd Toeplitz +
// bwd Hankel rings R[8]/Rb[8] (b128 reads, 8 parity copies), g' global ring
// ga[2][2] distance-2. 4 waves/SIMD (<=128 regs), 1024 blocks = 2 exact
// rounds at 2 blocks/CU. Staging window amortized over 512 outputs.
// ---------------------------------------------------------------------------
__global__ __launch_bounds__(512, 4) void bp_mfma(
    const float* __restrict__ x, const _Float16* __restrict__ gbuf,
    float* __restrict__ out)
{
    __shared__ __align__(16) _Float16 lds[LDS_H];

    const int blk  = blockIdx.x;
    const int tile = blk & 15;              // L/TB = 16
    const int b    = blk >> 4;
    const int tid  = threadIdx.x;
    const int l    = tid & 63;
    const int w    = tid >> 6;              // 0..7

    const int T0 = tile * TB;
    const int P0 = T0 + OFFSET;
    const float* __restrict__ xrow = x + b * L_;

    // ---- two-phase staging: global loads first, then LDS parity-copy writes
    // fwd: xf[i] = xp[P0 + i];  bwd: xr[j] = xp[P0 + CREF - j]
    float fv[3], bv[3];
    #pragma unroll
    for (int r = 0; r < 3; ++r) {
        const int i = tid + 512 * r;
        if (i < NWF) {
            const int p = P0 + i;
            fv[r] = (p < PADLEN) ? -xrow[PADLEN - p]
                  : (p < PADLEN + L_) ? xrow[p - PADLEN]
                  : -xrow[(L_ - 2) + (PADLEN + L_) - p];
            const int p2 = P0 + CREF - i;
            bv[r] = (p2 < PADLEN) ? -xrow[PADLEN - p2]
                  : (p2 < PADLEN + L_) ? xrow[p2 - PADLEN]
                  : -xrow[(L_ - 2) + (PADLEN + L_) - p2];
        }
    }
    #pragma unroll
    for (int r = 0; r < 3; ++r) {
        const int i = tid + 512 * r;
        if (i < NWF) {
            const _Float16 hf = (_Float16)fv[r];
            const _Float16 hb = (_Float16)bv[r];
            #pragma unroll
            for (int cc = 0; cc < 8; ++cc) {
                if (i - cc >= 0) {
                    lds[cc * CPF + (i - cc)] = hf;
                    lds[XB + cc * CPF + (i - cc)] = hb;
                }
            }
        }
    }
    __syncthreads();          // the only barrier

    const int g4 = l >> 4;                  // k-group 0..3
    const int t4 = l & 15;                  // t within subtile / A row
    const int cf = t4 & 7;                  // fwd parity copy
    const int cb = (-t4) & 7;               // bwd parity copy

    f32x4 acc0[4], acc1[4];
    #pragma unroll
    for (int q = 0; q < 4; ++q) {
        acc0[q] = (f32x4){0.f, 0.f, 0.f, 0.f};
        acc1[q] = (f32x4){0.f, 0.f, 0.f, 0.f};
    }

    // fwd slot a: per-lane pos = base_f + 16a, base_f = 64w + t4 + 8*g4
    // bwd slot b: per-lane pos = base_b + 16b, base_b = 576 - 64w - t4 + 8*g4
    const int base_f = 64 * w + t4 + 8 * g4;
    const int base_b = 576 - 64 * w - t4 + 8 * g4;
    const char* lbf0 = (const char*)lds + 2 * (cf * CPF + (base_f - cf));
    const char* lbb0 = (const char*)lds + 2 * (XB + cb * CPF + (base_b - cb));

    half8 R[8], Rb[8];
    #pragma unroll
    for (int a = 0; a < 8; ++a)
        R[a] = *(const half8*)(lbf0 + 32 * a);
    Rb[0] = *(const half8*)(lbb0);
    #pragma unroll
    for (int j = 1; j < 8; ++j)
        Rb[j] = *(const half8*)(lbb0 - 32 * (8 - j));

    // g A-fragment ring: ga[S&1][tau]; prefetch distance 2 steps.
    const half8* __restrict__ gp = (const half8*)gbuf + l;
    half8 ga[2][2];
    ga[0][0] = gp[0];   ga[0][1] = gp[64];
    ga[1][0] = gp[128]; ga[1][1] = gp[192];

    for (int n = 0; n < 6; ++n) {           // 6 x 4 steps = 24
        const char* lbf = lbf0 + 256 * n;   // 64 * 4n
        const char* lbb = lbb0 + 256 * n;
        const half8* gpn = gp + 128 * 4 * n;
        #pragma unroll
        for (int k4 = 0; k4 < 4; ++k4) {    // S = 4n + k4; all indices static
            const int p = 2 * k4;
            const int sel = k4 & 1;
            __builtin_amdgcn_s_setprio(1);
            #pragma unroll
            for (int q = 0; q < 4; ++q) {
                const half8 Bq = R[(p + q) & 7] + Rb[(p + 8 - q) & 7];
                acc0[q] = MFMA16(ga[sel][0], Bq, acc0[q]);
                acc1[q] = MFMA16(ga[sel][1], Bq, acc1[q]);
            }
            __builtin_amdgcn_s_setprio(0);
            // fwd refills a = 2S+8, 2S+9 -> bytes 64S+256, +288
            R[p & 7]        = *(const half8*)(lbf + 64 * k4 + 256);
            R[(p + 1) & 7]  = *(const half8*)(lbf + 64 * k4 + 288);
            // bwd refills b = 2S+1, 2S+2 -> bytes 64S+32, +64
            Rb[(p + 1) & 7] = *(const half8*)(lbb + 64 * k4 + 32);
            Rb[(p + 2) & 7] = *(const half8*)(lbb + 64 * k4 + 64);
            // g prefetch step S+2 (zeros beyond 25: blind-safe)
            ga[sel][0] = gpn[(k4 + 2) * 128];
            ga[sel][1] = gpn[(k4 + 2) * 128 + 64];
        }
    }

    // tail: S = 24, p = 0; R[q] holds a = 48+q, Rb[(8-q)&7] holds b = 48-q;
    // ga[0] was refilled at S=22 with step 24's fragments.
    __builtin_amdgcn_s_setprio(1);
    #pragma unroll
    for (int q = 0; q < 4; ++q) {
        const half8 Bq = R[q & 7] + Rb[(8 - q) & 7];
        acc0[q] = MFMA16(ga[0][0], Bq, acc0[q]);
        acc1[q] = MFMA16(ga[0][1], Bq, acc1[q]);
    }
    __builtin_amdgcn_s_setprio(0);

    // D layout (m89, 16x16): col = l&15, row = (l>>4)*4 + r
    const float sc = 1.0f / 1024.0f;
    #pragma unroll
    for (int q = 0; q < 4; ++q) {
        const int tb = T0 + 64 * w + 16 * q + t4;
        #pragma unroll
        for (int r = 0; r < 4; ++r) {
            const int o0 = 4 * g4 + r;          // bands 0..15
            __builtin_nontemporal_store(acc0[q][r] * sc,
                                        &out[((b * NB_ + o0) << 13) + tb]);
        }
        if (g4 == 0) {
            #pragma unroll
            for (int r = 0; r < 4; ++r) {
                const int o1 = 16 + r;          // bands 16..19
                __builtin_nontemporal_store(acc1[q][r] * sc,
                                            &out[((b * NB_ + o1) << 13) + tb]);
            }
        }
    }
}

extern "C" void kernel_launch(void* const* d_in, const int* in_sizes, int n_in,
                              void* d_out, int out_size, void* d_ws, size_t ws_size,
                              hipStream_t stream)
{
    const float* x    = (const float*)d_in[0];   // (B,1,L) f32
    const float* kern = (const float*)d_in[1];   // (NB,K) f32
    float*       out  = (float*)d_out;           // (B,1,NB,L) f32

    _Float16* gbuf = (_Float16*)d_ws;            // 28*2*64*16 = 57344 B

    bp_filter<<<32, 256, 0, stream>>>(kern, gbuf);
    bp_mfma<<<B_ * (L_ / TB), 512, 0, stream>>>(x, gbuf, out);
}

// Round 20
// 42.621 us; speedup vs baseline: 1.3309x; 1.3309x over previous
//
#include <hip/hip_runtime.h>

#define B_      64
#define L_      8192
#define NB_     20
#define K_      769
#define GLEN    1537        // 2K-1 combined filter length
#define GSM     1552        // g row length (f32)
#define NST3    25          // folded K-steps of 32 taps: 25*32 = 800 >= 785
#define NSTP3   28          // packed steps in gbuf (zeros beyond 25) for blind prefetch
#define TB      256         // t-tile per block (4 waves x 64 t, 4 x 16-t subtiles/wave)
#define CPF     1176        // copy stride (halves): byte 2352 mod 128 = 48
#define NWF     1120        // fwd staged halves per copy (max read 1118)
#define NWB     1128        // bwd staged halves per copy (max read 1119)
#define XB      (8 * CPF)   // bwd region offset (halves)
#define LDS_H   (16 * CPF)  // 18816 halves = 37632 B -> 4 blocks/CU
#define CREF    1856        // bwd staging: xr[j] = xp[P0 + CREF - j]
#define PADLEN  2307        // min(3K, L-1)
#define OFFSET  1539        // PADLEN - (K-1)
#define PBUF    (NB_ * GSM) // partial-g buffer stride (floats)

typedef _Float16 half8  __attribute__((ext_vector_type(8)));
typedef float    f32x4  __attribute__((ext_vector_type(4)));

#define MFMA16(a, b, c) __builtin_amdgcn_mfma_f32_16x16x32_f16((a), (b), (c), 0, 0, 0)

// ---------------------------------------------------------------------------
// Kernel 1: partial autocorrelation, lane-paired (2 lanes per m, half-length
// serial chains) + finer m-grid. grid (NB, 16, 4) x 256.
// ---------------------------------------------------------------------------
__global__ __launch_bounds__(256) void bp_combine(
    const float* __restrict__ kern, float* __restrict__ gpart)
{
    __shared__ __align__(16) float ks[K_];
    const int o   = blockIdx.x;
    const int jc  = blockIdx.z;
    const int tid = threadIdx.x;
    for (int i = tid; i < K_; i += 256) ks[i] = kern[o * K_ + i];
    __syncthreads();

    const int m = blockIdx.y * 97 + (tid >> 1);
    if (tid < 194 && m < GSM) {
        int jlo = (m > K_ - 1) ? (m - (K_ - 1)) : 0;
        int jhi = (m < K_ - 1) ? m : (K_ - 1);
        if (jlo < jc * 193) jlo = jc * 193;
        if (jhi > jc * 193 + 192) jhi = jc * 193 + 192;
        const int jmid = (jlo + jhi + 1) >> 1;
        const int ja = (tid & 1) ? jmid : jlo;
        const int jb = (tid & 1) ? jhi  : jmid - 1;
        float acc = 0.f;
        for (int j = ja; j <= jb; ++j)
            acc = fmaf(ks[K_ - 1 - j], ks[m - j], acc);
        acc += __shfl_xor(acc, 1);
        if (!(tid & 1)) gpart[jc * PBUF + o * GSM + m] = acc;
    }
}

// ---------------------------------------------------------------------------
// Kernel 2: folded filter g' packed for mfma_f32_16x16x32_f16 A-fragments.
// g'[tap<768] = g[tap]; g'[768] = g[768]/2; g'[>768] = 0. Scaled x1024.
// Fragment f = (step*2 + tau)*64 + l: elem e = g'[o = 16*tau + (l&15),
//                                               32*step + 8*(l>>4) + e]
// ---------------------------------------------------------------------------
__global__ __launch_bounds__(256) void bp_pack(
    const float* __restrict__ gpart, _Float16* __restrict__ gbuf)
{
    const int t = blockIdx.x * 256 + threadIdx.x;
    if (t >= NSTP3 * 2 * 64) return;
    const int l    = t & 63;
    const int tau  = (t >> 6) & 1;
    const int step = t >> 7;
    const int g4   = l >> 4;
    const int o    = 16 * tau + (l & 15);
    half8 f;
    #pragma unroll
    for (int e = 0; e < 8; ++e) {
        const int tap = 32 * step + 8 * g4 + e;
        float v = 0.f;
        if (o < NB_ && tap <= 768) {
            const int idx = o * GSM + tap;
            const float gg = gpart[idx] + gpart[PBUF + idx] +
                             gpart[2 * PBUF + idx] + gpart[3 * PBUF + idx];
            v = gg * (tap == 768 ? 512.0f : 1024.0f);
        }
        f[e] = (_Float16)v;
    }
    *((half8*)gbuf + t) = f;
}

// ---------------------------------------------------------------------------
// Kernel 3 (folded, 16x16x32, LOW-REG): 4 subtiles/wave, TB=256.
// acc 32 + R[8]/Rb[8] 64 + ga 16 + addr ~12 -> <=128 regs -> 4 waves/SIMD.
// Best measured config (r16: 42.8 us). Ring algebra: fwd Toeplitz slot a,
// bwd Hankel slot b; B-operand = R[(p+q)&7] + Rb[(p-q)&7]; 2+2 b128
// refills + 2 g-prefetches per 8-MFMA step. LDS 36.8 KB -> 4 blocks/CU.
// ---------------------------------------------------------------------------
__global__ __launch_bounds__(256, 4) void bp_mfma(
    const float* __restrict__ x, const _Float16* __restrict__ gbuf,
    float* __restrict__ out)
{
    __shared__ __align__(16) _Float16 lds[LDS_H];

    const int blk  = blockIdx.x;
    const int tile = blk & 31;              // L/TB = 32
    const int b    = blk >> 5;
    const int tid  = threadIdx.x;
    const int l    = tid & 63;
    const int w    = tid >> 6;

    const int T0 = tile * TB;
    const int P0 = T0 + OFFSET;
    const float* __restrict__ xrow = x + b * L_;

    // ---- two-phase staging: global loads first, then LDS parity-copy writes
    // fwd: xf[i] = xp[P0 + i];  bwd: xr[j] = xp[P0 + CREF - j]
    float fv[5], bv[5];
    #pragma unroll
    for (int r = 0; r < 5; ++r) {
        const int i = tid + 256 * r;
        if (i < NWF) {
            const int p = P0 + i;
            fv[r] = (p < PADLEN) ? -xrow[PADLEN - p]
                  : (p < PADLEN + L_) ? xrow[p - PADLEN]
                  : -xrow[(L_ - 2) + (PADLEN + L_) - p];
        }
        if (i < NWB) {
            const int p2 = P0 + CREF - i;
            bv[r] = (p2 < PADLEN) ? -xrow[PADLEN - p2]
                  : (p2 < PADLEN + L_) ? xrow[p2 - PADLEN]
                  : -xrow[(L_ - 2) + (PADLEN + L_) - p2];
        }
    }
    #pragma unroll
    for (int r = 0; r < 5; ++r) {
        const int i = tid + 256 * r;
        if (i < NWF) {
            const _Float16 h = (_Float16)fv[r];
            #pragma unroll
            for (int cc = 0; cc < 8; ++cc)
                if (i - cc >= 0) lds[cc * CPF + (i - cc)] = h;
        }
        if (i < NWB) {
            const _Float16 h = (_Float16)bv[r];
            #pragma unroll
            for (int cc = 0; cc < 8; ++cc)
                if (i - cc >= 0) lds[XB + cc * CPF + (i - cc)] = h;
        }
    }
    __syncthreads();          // the only barrier

    const int g4 = l >> 4;                  // k-group 0..3
    const int t4 = l & 15;                  // t within subtile / A row
    const int cf = l & 7;                   // fwd parity copy (pos mod 8)
    const int cb = (16 - t4) & 7;           // bwd parity copy (pos mod 8)

    f32x4 acc0[4], acc1[4];
    #pragma unroll
    for (int q = 0; q < 4; ++q) {
        acc0[q] = (f32x4){0.f, 0.f, 0.f, 0.f};
        acc1[q] = (f32x4){0.f, 0.f, 0.f, 0.f};
    }

    // fwd slot a: per-lane pos = base_f + 16a, base_f = 64w + t4 + 8*g4
    // bwd slot b: per-lane pos = base_b + 16b, base_b = 320 - 64w - t4 + 8*g4
    const int base_f = 64 * w + t4 + 8 * g4;
    const int base_b = 320 - 64 * w - t4 + 8 * g4;
    const char* lbf0 = (const char*)lds + 2 * (cf * CPF + (base_f - cf));
    const char* lbb0 = (const char*)lds + 2 * (XB + cb * CPF + (base_b - cb));

    half8 R[8], Rb[8];
    #pragma unroll
    for (int a = 0; a < 8; ++a)
        R[a] = *(const half8*)(lbf0 + 32 * a);
    Rb[0] = *(const half8*)(lbb0);
    #pragma unroll
    for (int j = 1; j < 8; ++j)
        Rb[j] = *(const half8*)(lbb0 - 32 * (8 - j));

    // g A-fragment ring: ga[S&1][tau]; prefetch distance 2 steps.
    const half8* __restrict__ gp = (const half8*)gbuf + l;
    half8 ga[2][2];
    ga[0][0] = gp[0];   ga[0][1] = gp[64];
    ga[1][0] = gp[128]; ga[1][1] = gp[192];

    for (int n = 0; n < 6; ++n) {           // 6 x 4 steps = 24
        const char* lbf = lbf0 + 256 * n;   // 64 * 4n
        const char* lbb = lbb0 + 256 * n;
        const half8* gpn = gp + 128 * 4 * n;
        #pragma unroll
        for (int k4 = 0; k4 < 4; ++k4) {    // S = 4n + k4; all indices static
            const int p = 2 * k4;
            const int sel = k4 & 1;
            __builtin_amdgcn_s_setprio(1);
            #pragma unroll
            for (int q = 0; q < 4; ++q) {
                const half8 Bq = R[(p + q) & 7] + Rb[(p + 8 - q) & 7];
                acc0[q] = MFMA16(ga[sel][0], Bq, acc0[q]);
                acc1[q] = MFMA16(ga[sel][1], Bq, acc1[q]);
            }
            __builtin_amdgcn_s_setprio(0);
            // refills: fwd a = 2S+8, 2S+9 -> bytes 64S+256, +288
            R[p & 7]        = *(const half8*)(lbf + 64 * k4 + 256);
            R[(p + 1) & 7]  = *(const half8*)(lbf + 64 * k4 + 288);
            // bwd b = 2S+1, 2S+2 -> bytes 64S+32, +64
            Rb[(p + 1) & 7] = *(const half8*)(lbb + 64 * k4 + 32);
            Rb[(p + 2) & 7] = *(const half8*)(lbb + 64 * k4 + 64);
            // g prefetch step S+2 (zeros beyond 25: blind-safe)
            ga[sel][0] = gpn[(k4 + 2) * 128];
            ga[sel][1] = gpn[(k4 + 2) * 128 + 64];
        }
    }

    // tail: S = 24, p = 0; R[q] holds a = 48+q, Rb[(8-q)&7] holds b = 48-q;
    // ga[0] was refilled at S=22 with step 24's fragments.
    __builtin_amdgcn_s_setprio(1);
    #pragma unroll
    for (int q = 0; q < 4; ++q) {
        const half8 Bq = R[q & 7] + Rb[(8 - q) & 7];
        acc0[q] = MFMA16(ga[0][0], Bq, acc0[q]);
        acc1[q] = MFMA16(ga[0][1], Bq, acc1[q]);
    }
    __builtin_amdgcn_s_setprio(0);

    // D layout (m89, 16x16): col = l&15, row = (l>>4)*4 + r
    const float sc = 1.0f / 1024.0f;
    #pragma unroll
    for (int q = 0; q < 4; ++q) {
        const int tb = T0 + 64 * w + 16 * q + t4;
        #pragma unroll
        for (int r = 0; r < 4; ++r) {
            const int o0 = 4 * g4 + r;          // bands 0..15
            __builtin_nontemporal_store(acc0[q][r] * sc,
                                        &out[((b * NB_ + o0) << 13) + tb]);
        }
        if (g4 == 0) {
            #pragma unroll
            for (int r = 0; r < 4; ++r) {
                const int o1 = 16 + r;          // bands 16..19
                __builtin_nontemporal_store(acc1[q][r] * sc,
                                            &out[((b * NB_ + o1) << 13) + tb]);
            }
        }
    }
}

extern "C" void kernel_launch(void* const* d_in, const int* in_sizes, int n_in,
                              void* d_out, int out_size, void* d_ws, size_t ws_size,
                              hipStream_t stream)
{
    const float* x    = (const float*)d_in[0];   // (B,1,L) f32
    const float* kern = (const float*)d_in[1];   // (NB,K) f32
    float*       out  = (float*)d_out;           // (B,1,NB,L) f32

    float*    gpart = (float*)d_ws;                           // 496640 B
    _Float16* gbuf  = (_Float16*)((char*)d_ws + 496640);      // 57344 B

    bp_combine<<<dim3(NB_, 16, 4), 256, 0, stream>>>(kern, gpart);
    bp_pack<<<14, 256, 0, stream>>>(gpart, gbuf);
    bp_mfma<<<B_ * (L_ / TB), 256, 0, stream>>>(x, gbuf, out);
}